// Round 5
// baseline (304.708 us; speedup 1.0000x reference)
//
#include <hip/hip_runtime.h>
#include <stdint.h>

typedef __bf16 bf16;
typedef bf16 bf16x8 __attribute__((ext_vector_type(8)));
typedef float f32x4 __attribute__((ext_vector_type(4)));

#define MFMA(a, b, c) __builtin_amdgcn_mfma_f32_16x16x32_bf16(a, b, c, 0, 0, 0)

// exp(0.25*s) = exp2(s * 0.25*log2(e)); scale folded into Qp at projection.
#define SCALE_L2E 0.3606737602222409f
#define M0 16.0f

__device__ __forceinline__ void gload_lds16(const void* g, void* l) {
  __builtin_amdgcn_global_load_lds(
      (const __attribute__((address_space(1))) uint32_t*)g,
      (__attribute__((address_space(3))) uint32_t*)l, 16, 0, 0);
}

// ---------------------------------------------------------------------------
// Kernel 1: Wt[z][n][k] = (bf16) W_z[k][n]
// ---------------------------------------------------------------------------
__global__ void k_wtrans(const float* __restrict__ Wq, const float* __restrict__ Wk,
                         const float* __restrict__ Wv, bf16* __restrict__ Wt) {
  int idx = blockIdx.x * 256 + threadIdx.x;
  int z = idx >> 18;
  int r = idx & 262143;
  int n = r >> 9, k = r & 511;
  const float* W = (z == 0) ? Wq : (z == 1) ? Wk : Wv;
  Wt[idx] = (bf16)W[k * 512 + n];
}

// ---------------------------------------------------------------------------
// Kernel 2: projection GEMM. z=0: Q (folds SCALE_L2E) -> Qp. z=1: K -> Kp.
// z=2: V -> Vtp TRANSPOSED (fused k_vtrans: C/D layout gives 4 consecutive
// t-rows per lane -> single 8B store per fragment).
// 4 blocks/CU; B staged via global_load_lds (bf16, contiguous rows).
// ---------------------------------------------------------------------------
__global__ __launch_bounds__(256, 4) void k_proj(
    const float* __restrict__ q, const float* __restrict__ k, const float* __restrict__ v,
    const bf16* __restrict__ Wt, const float* __restrict__ bq, const float* __restrict__ bk,
    const float* __restrict__ bv, bf16* __restrict__ Qp, bf16* __restrict__ Kp,
    bf16* __restrict__ Vtp) {
  int z = blockIdx.z;
  const float* A = (z == 0) ? q : (z == 1) ? k : v;
  const float* bias = (z == 0) ? bq : (z == 1) ? bk : bv;
  const bf16* Bw = Wt + (size_t)z * 512 * 512;

  int m0 = blockIdx.x * 128, n0 = blockIdx.y * 128;
  __shared__ bf16 As[128 * 40];   // padded (VALU-staged, f32->bf16 convert)
  __shared__ bf16 Bs[128 * 32];   // unpadded (global_load_lds, m97 layout)

  int tid = threadIdx.x;
  int wave = tid >> 6, lane = tid & 63, qr = lane & 15, quad = lane >> 4;
  int wm = (wave >> 1) * 64, wn = (wave & 1) * 64;

  f32x4 acc[4][4];
  for (int mi = 0; mi < 4; mi++)
    for (int ni = 0; ni < 4; ni++) acc[mi][ni] = (f32x4){0.f, 0.f, 0.f, 0.f};

  for (int k0 = 0; k0 < 512; k0 += 32) {
    __syncthreads();
    for (int i = 0; i < 2; i++) {
      int ch = i * 256 + tid;          // 0..511
      int row = ch >> 2, c = ch & 3;
      gload_lds16(Bw + (size_t)(n0 + row) * 512 + k0 + c * 8, &Bs[ch * 8]);
      const float4* src = (const float4*)(A + (size_t)(m0 + row) * 512 + k0 + c * 8);
      float4 x = src[0], y = src[1];
      bf16x8 t;
      t[0] = (bf16)x.x; t[1] = (bf16)x.y; t[2] = (bf16)x.z; t[3] = (bf16)x.w;
      t[4] = (bf16)y.x; t[5] = (bf16)y.y; t[6] = (bf16)y.z; t[7] = (bf16)y.w;
      *(bf16x8*)&As[row * 40 + c * 8] = t;
    }
    __syncthreads();
    bf16x8 af[4], bfv[4];
    for (int mi = 0; mi < 4; mi++)
      af[mi] = *(bf16x8*)&As[(wm + mi * 16 + qr) * 40 + quad * 8];
    for (int ni = 0; ni < 4; ni++)
      bfv[ni] = *(bf16x8*)&Bs[(wn + ni * 16 + qr) * 32 + quad * 8];
    for (int mi = 0; mi < 4; mi++)
      for (int ni = 0; ni < 4; ni++) acc[mi][ni] = MFMA(af[mi], bfv[ni], acc[mi][ni]);
  }

  if (z == 2) {
    // transposed store: Vtp[b*512 + h][t], 4 consecutive t per lane -> 8B store
    for (int ni = 0; ni < 4; ni++) {
      int col = n0 + wn + ni * 16 + qr;   // h
      float bz = bias[col];
      for (int mi = 0; mi < 4; mi++) {
        int rbase = m0 + wm + mi * 16 + quad * 4;   // global row = b*2048 + t
        int bb = rbase >> 11, tt = rbase & 2047;
        bf16 tmp[4];
        for (int r = 0; r < 4; r++) tmp[r] = (bf16)(acc[mi][ni][r] + bz);
        *(uint64_t*)(Vtp + ((size_t)(bb * 512 + col)) * 2048 + tt) = *(uint64_t*)tmp;
      }
    }
  } else {
    bf16* C = (z == 0) ? Qp : Kp;
    float sc = (z == 0) ? SCALE_L2E : 1.0f;
    for (int ni = 0; ni < 4; ni++) {
      int col = n0 + wn + ni * 16 + qr;
      float bz = bias[col];
      for (int mi = 0; mi < 4; mi++) {
        int rbase = m0 + wm + mi * 16 + quad * 4;
        for (int r = 0; r < 4; r++)
          C[(size_t)(rbase + r) * 512 + col] = (bf16)((acc[mi][ni][r] + bz) * sc);
      }
    }
  }
}

// ---------------------------------------------------------------------------
// Kernel 3: QK^T GEMM with exp2 epilogue (m97 structure, 3 blocks/CU).
// Out: P[b][q][key] = exp2(s - M0) bf16; Lpart[slice][b*2048+q] row-partials.
// ---------------------------------------------------------------------------
__global__ __launch_bounds__(256, 3) void k_qk(const bf16* __restrict__ Qp,
                                               const bf16* __restrict__ Kp,
                                               bf16* __restrict__ P,
                                               float* __restrict__ Lpart) {
  __shared__ bf16 As[128 * 32];
  __shared__ bf16 Bs[128 * 32];
  int b = blockIdx.z;
  const bf16* A = Qp + (size_t)b * 2048 * 512;
  const bf16* B = Kp + (size_t)b * 2048 * 512;
  bf16* Pb = P + (size_t)b * 2048 * 2048;
  int m0 = blockIdx.x * 128, n0 = blockIdx.y * 128;
  int tid = threadIdx.x;
  int wave = tid >> 6, lane = tid & 63, qr = lane & 15, quad = lane >> 4;
  int wm = (wave >> 1) * 64, wn = (wave & 1) * 64;

  f32x4 acc[4][4];
  for (int mi = 0; mi < 4; mi++)
    for (int ni = 0; ni < 4; ni++) acc[mi][ni] = (f32x4){0.f, 0.f, 0.f, 0.f};

  for (int k0 = 0; k0 < 512; k0 += 32) {
    __syncthreads();
    for (int i = 0; i < 2; i++) {
      int ch = i * 256 + tid;
      int row = ch >> 2, c = ch & 3;
      gload_lds16(A + (size_t)(m0 + row) * 512 + k0 + c * 8, &As[ch * 8]);
      gload_lds16(B + (size_t)(n0 + row) * 512 + k0 + c * 8, &Bs[ch * 8]);
    }
    __syncthreads();
    bf16x8 af[4], bfv[4];
    for (int mi = 0; mi < 4; mi++)
      af[mi] = *(bf16x8*)&As[(wm + mi * 16 + qr) * 32 + quad * 8];
    for (int ni = 0; ni < 4; ni++)
      bfv[ni] = *(bf16x8*)&Bs[(wn + ni * 16 + qr) * 32 + quad * 8];
    for (int mi = 0; mi < 4; mi++)
      for (int ni = 0; ni < 4; ni++) acc[mi][ni] = MFMA(af[mi], bfv[ni], acc[mi][ni]);
  }

  int slice = blockIdx.y * 2 + (wave & 1);   // 32 slices of 64 keys each
  float* Lp = Lpart + (size_t)slice * 16384 + b * 2048;
  for (int mi = 0; mi < 4; mi++) {
    int rowb = m0 + wm + mi * 16 + quad * 4;
    for (int r = 0; r < 4; r++) {
      float s = 0.f;
      bf16* prow = Pb + (size_t)(rowb + r) * 2048 + n0 + wn + qr;
      for (int ni = 0; ni < 4; ni++) {
        float e = exp2f(acc[mi][ni][r] - M0);
        prow[ni * 16] = (bf16)e;
        s += e;
      }
      s += __shfl_xor(s, 1);
      s += __shfl_xor(s, 2);
      s += __shfl_xor(s, 4);
      s += __shfl_xor(s, 8);
      if (qr == 0) Lp[rowb + r] = s;
    }
  }
}

// ---------------------------------------------------------------------------
// Kernel 4: Linv[q] = 1 / sum_{32 slices} Lpart[slice][q]
// ---------------------------------------------------------------------------
__global__ void k_lred(const float* __restrict__ Lpart, float* __restrict__ Linv) {
  int i = blockIdx.x * 256 + threadIdx.x;
  float s = 0.f;
  for (int j = 0; j < 32; j++) s += Lpart[(size_t)j * 16384 + i];
  Linv[i] = 1.0f / s;
}

// ---------------------------------------------------------------------------
// Kernel 5: PV GEMM, 64x128 tile (1024 blocks -> 4 resident/CU).
// A = P[b] [2048 x 2048], B = Vtp[b] [512 x 2048] (h-major, keys contig).
// ---------------------------------------------------------------------------
__global__ __launch_bounds__(256, 4) void k_pv(const bf16* __restrict__ P,
                                               const bf16* __restrict__ Vtp,
                                               const float* __restrict__ Linv,
                                               float* __restrict__ out) {
  __shared__ bf16 As[64 * 32];
  __shared__ bf16 Bs[128 * 32];
  int b = blockIdx.z;
  const bf16* A = P + (size_t)b * 2048 * 2048;
  const bf16* B = Vtp + (size_t)b * 512 * 2048;
  int m0 = blockIdx.x * 64, n0 = blockIdx.y * 128;   // m over q, n over h
  int tid = threadIdx.x;
  int wave = tid >> 6, lane = tid & 63, qr = lane & 15, quad = lane >> 4;
  int wm = (wave >> 1) * 32, wn = (wave & 1) * 64;

  f32x4 acc[2][4];
  for (int mi = 0; mi < 2; mi++)
    for (int ni = 0; ni < 4; ni++) acc[mi][ni] = (f32x4){0.f, 0.f, 0.f, 0.f};

  for (int k0 = 0; k0 < 2048; k0 += 32) {
    __syncthreads();
    {
      int row = tid >> 2, c = tid & 3;   // 256 chunks for A (64 rows x 4)
      gload_lds16(A + (size_t)(m0 + row) * 2048 + k0 + c * 8, &As[tid * 8]);
    }
    for (int i = 0; i < 2; i++) {
      int ch = i * 256 + tid;            // 512 chunks for B (128 rows x 4)
      int row = ch >> 2, c = ch & 3;
      gload_lds16(B + (size_t)(n0 + row) * 2048 + k0 + c * 8, &Bs[ch * 8]);
    }
    __syncthreads();
    bf16x8 af[2], bfv[4];
    for (int mi = 0; mi < 2; mi++)
      af[mi] = *(bf16x8*)&As[(wm + mi * 16 + qr) * 32 + quad * 8];
    for (int ni = 0; ni < 4; ni++)
      bfv[ni] = *(bf16x8*)&Bs[(wn + ni * 16 + qr) * 32 + quad * 8];
    for (int mi = 0; mi < 2; mi++)
      for (int ni = 0; ni < 4; ni++) acc[mi][ni] = MFMA(af[mi], bfv[ni], acc[mi][ni]);
  }

  for (int mi = 0; mi < 2; mi++) {
    int rowb = m0 + wm + mi * 16 + quad * 4;
    float linv[4];
    for (int r = 0; r < 4; r++) linv[r] = Linv[b * 2048 + rowb + r];
    for (int ni = 0; ni < 4; ni++) {
      int col = n0 + wn + ni * 16 + qr;
      float* og = out + (size_t)(b * 2048 + rowb) * 512 + col;
      for (int r = 0; r < 4; r++) og[(size_t)r * 512] = acc[mi][ni][r] * linv[r];
    }
  }
}

// ---------------------------------------------------------------------------
extern "C" void kernel_launch(void* const* d_in, const int* in_sizes, int n_in,
                              void* d_out, int out_size, void* d_ws, size_t ws_size,
                              hipStream_t stream) {
  (void)in_sizes; (void)n_in; (void)out_size; (void)ws_size;
  const float* q  = (const float*)d_in[0];
  const float* k  = (const float*)d_in[1];
  const float* v  = (const float*)d_in[2];
  const float* Wq = (const float*)d_in[3];
  const float* bq = (const float*)d_in[4];
  const float* Wk = (const float*)d_in[5];
  const float* bk = (const float*)d_in[6];
  const float* Wv = (const float*)d_in[7];
  const float* bv = (const float*)d_in[8];
  float* out = (float*)d_out;

  char* ws = (char*)d_ws;
  bf16* Wt     = (bf16*)(ws);                 // 1,572,864 B
  bf16* Qp     = (bf16*)(ws + 1572864);       // 16 MiB
  bf16* Kp     = (bf16*)(ws + 18350080);      // 16 MiB
  bf16* Vtp    = (bf16*)(ws + 35127296);      // 16 MiB (written by k_proj z=2)
  bf16* P      = (bf16*)(ws + 51904512);      // 64 MiB
  float* Lpart = (float*)(ws + 119013376);    // 2 MiB
  float* Linv  = (float*)(ws + 121110528);    // 64 KiB (total ~115.6 MiB)

  k_wtrans<<<3072, 256, 0, stream>>>(Wq, Wk, Wv, Wt);
  k_proj<<<dim3(128, 4, 3), 256, 0, stream>>>(q, k, v, Wt, bq, bk, bv, Qp, Kp, Vtp);
  k_qk<<<dim3(16, 16, 8), 256, 0, stream>>>(Qp, Kp, P, Lpart);
  k_lred<<<64, 256, 0, stream>>>(Lpart, Linv);
  k_pv<<<dim3(32, 4, 8), 256, 0, stream>>>(P, Vtp, Linv, out);
}

// Round 6
// 274.781 us; speedup vs baseline: 1.1089x; 1.1089x over previous
//
#include <hip/hip_runtime.h>
#include <stdint.h>

typedef __bf16 bf16;
typedef bf16 bf16x8 __attribute__((ext_vector_type(8)));
typedef float f32x4 __attribute__((ext_vector_type(4)));

#define MFMA(a, b, c) __builtin_amdgcn_mfma_f32_16x16x32_bf16(a, b, c, 0, 0, 0)

// exp(0.25*s) = exp2(s * 0.25*log2(e)); scale folded into Qp at projection.
#define SCALE_L2E 0.3606737602222409f
#define M0 16.0f

__device__ __forceinline__ void gload_lds16(const void* g, void* l) {
  __builtin_amdgcn_global_load_lds(
      (const __attribute__((address_space(1))) uint32_t*)g,
      (__attribute__((address_space(3))) uint32_t*)l, 16, 0, 0);
}

// ---------------------------------------------------------------------------
// Kernel 1: Wt[z][n][k] = (bf16) W_z[k][n] — LDS-tiled transpose, coalesced
// both sides. grid (16,16,3), block (32,8).
// ---------------------------------------------------------------------------
__global__ void k_wtrans(const float* __restrict__ Wq, const float* __restrict__ Wk,
                         const float* __restrict__ Wv, bf16* __restrict__ Wt) {
  __shared__ float tile[32][33];
  int x = threadIdx.x, y = threadIdx.y;
  int k0 = blockIdx.x * 32, n0 = blockIdx.y * 32, z = blockIdx.z;
  const float* W = (z == 0) ? Wq : (z == 1) ? Wk : Wv;
  for (int j = 0; j < 4; j++)
    tile[y + 8 * j][x] = W[(size_t)(k0 + y + 8 * j) * 512 + n0 + x];
  __syncthreads();
  bf16* o = Wt + (size_t)z * 262144;
  for (int j = 0; j < 4; j++)
    o[(size_t)(n0 + y + 8 * j) * 512 + k0 + x] = (bf16)tile[x][y + 8 * j];
}

// ---------------------------------------------------------------------------
// Kernel 2: projection GEMM, BK=64 (32 MFMA/wave per barrier).
// z=0: Q (folds SCALE_L2E) -> Qp. z=1: K -> Kp. z=2: V -> Vtp transposed via
// LDS round-trip (coalesced stores; reuses staging LDS).
// A f32 VALU-staged+converted (padded LDS); B bf16 via global_load_lds with
// XOR chunk swizzle (slot c holds global chunk c^(row&7)).
// ---------------------------------------------------------------------------
__global__ __launch_bounds__(256, 3) void k_proj(
    const float* __restrict__ q, const float* __restrict__ k, const float* __restrict__ v,
    const bf16* __restrict__ Wt, const float* __restrict__ bq, const float* __restrict__ bk,
    const float* __restrict__ bv, bf16* __restrict__ Qp, bf16* __restrict__ Kp,
    bf16* __restrict__ Vtp) {
  int z = blockIdx.z;
  const float* A = (z == 0) ? q : (z == 1) ? k : v;
  const float* bias = (z == 0) ? bq : (z == 1) ? bk : bv;
  const bf16* Bw = Wt + (size_t)z * 262144;

  int m0 = blockIdx.x * 128, n0 = blockIdx.y * 128;
  __shared__ __align__(16) char smem[34816];
  bf16* As = (bf16*)smem;            // 128 x 72 (padded, VALU-staged)
  bf16* Bs = (bf16*)(smem + 18432);  // 128 x 64 (gload, swizzled)
  bf16* Ts = (bf16*)smem;            // epilogue reuse: 128 x 136

  int tid = threadIdx.x;
  int wave = tid >> 6, lane = tid & 63, qr = lane & 15, quad = lane >> 4;
  int wm = (wave >> 1) * 64, wn = (wave & 1) * 64;

  f32x4 acc[4][4];
  for (int mi = 0; mi < 4; mi++)
    for (int ni = 0; ni < 4; ni++) acc[mi][ni] = (f32x4){0.f, 0.f, 0.f, 0.f};

  for (int k0 = 0; k0 < 512; k0 += 64) {
    __syncthreads();
    for (int i = 0; i < 4; i++) {
      int ch = i * 256 + tid;          // 1024 chunks: 128 rows x 8
      int row = ch >> 3, c = ch & 7;
      int cs = c ^ (row & 7);
      gload_lds16(Bw + (size_t)(n0 + row) * 512 + k0 + cs * 8, &Bs[ch * 8]);
      const float4* src = (const float4*)(A + (size_t)(m0 + row) * 512 + k0 + c * 8);
      float4 x = src[0], y = src[1];
      bf16x8 t;
      t[0] = (bf16)x.x; t[1] = (bf16)x.y; t[2] = (bf16)x.z; t[3] = (bf16)x.w;
      t[4] = (bf16)y.x; t[5] = (bf16)y.y; t[6] = (bf16)y.z; t[7] = (bf16)y.w;
      *(bf16x8*)&As[row * 72 + c * 8] = t;
    }
    __syncthreads();
    for (int h = 0; h < 2; h++) {
      bf16x8 af[4], bfv[4];
      for (int mi = 0; mi < 4; mi++)
        af[mi] = *(bf16x8*)&As[(wm + mi * 16 + qr) * 72 + h * 32 + quad * 8];
      for (int ni = 0; ni < 4; ni++) {
        int rr = wn + ni * 16 + qr;
        int cc = (h * 4 + quad) ^ (rr & 7);
        bfv[ni] = *(bf16x8*)&Bs[rr * 64 + cc * 8];
      }
      for (int mi = 0; mi < 4; mi++)
        for (int ni = 0; ni < 4; ni++) acc[mi][ni] = MFMA(af[mi], bfv[ni], acc[mi][ni]);
    }
  }

  if (z == 2) {
    // V: transpose via LDS, then coalesced stores to Vtp[b*512+h][t]
    __syncthreads();
    for (int ni = 0; ni < 4; ni++) {
      int hcol = wn + ni * 16 + qr;          // local h 0..127
      float bz = bias[n0 + hcol];
      for (int mi = 0; mi < 4; mi++) {
        int tl = wm + mi * 16 + quad * 4;    // local t base
        bf16 tmp[4];
        for (int r = 0; r < 4; r++) tmp[r] = (bf16)(acc[mi][ni][r] + bz);
        *(uint64_t*)&Ts[hcol * 136 + tl] = *(uint64_t*)tmp;
      }
    }
    __syncthreads();
    int bb = m0 >> 11, t0l = m0 & 2047;
    for (int i = 0; i < 8; i++) {
      int ch = i * 256 + tid;                // 2048 chunks: 128 h x 16
      int row = ch >> 4, c = ch & 15;
      *(bf16x8*)(Vtp + (size_t)(bb * 512 + n0 + row) * 2048 + t0l + c * 8) =
          *(bf16x8*)&Ts[row * 136 + c * 8];
    }
  } else {
    bf16* C = (z == 0) ? Qp : Kp;
    float sc = (z == 0) ? SCALE_L2E : 1.0f;
    for (int ni = 0; ni < 4; ni++) {
      int col = n0 + wn + ni * 16 + qr;
      float bz = bias[col];
      for (int mi = 0; mi < 4; mi++) {
        int rbase = m0 + wm + mi * 16 + quad * 4;
        for (int r = 0; r < 4; r++)
          C[(size_t)(rbase + r) * 512 + col] = (bf16)((acc[mi][ni][r] + bz) * sc);
      }
    }
  }
}

// ---------------------------------------------------------------------------
// Kernel 3: QK^T GEMM, BK=64, exp2 epilogue. Both operands via gload+swizzle.
// Out: P[b][q][key] = exp2(s - M0) bf16; Lpart[slice][b*2048+q] row-partials.
// ---------------------------------------------------------------------------
__global__ __launch_bounds__(256, 3) void k_qk(const bf16* __restrict__ Qp,
                                               const bf16* __restrict__ Kp,
                                               bf16* __restrict__ P,
                                               float* __restrict__ Lpart) {
  __shared__ bf16 As[128 * 64];
  __shared__ bf16 Bs[128 * 64];
  int b = blockIdx.z;
  const bf16* A = Qp + (size_t)b * 2048 * 512;
  const bf16* B = Kp + (size_t)b * 2048 * 512;
  bf16* Pb = P + (size_t)b * 2048 * 2048;
  int m0 = blockIdx.x * 128, n0 = blockIdx.y * 128;
  int tid = threadIdx.x;
  int wave = tid >> 6, lane = tid & 63, qr = lane & 15, quad = lane >> 4;
  int wm = (wave >> 1) * 64, wn = (wave & 1) * 64;

  f32x4 acc[4][4];
  for (int mi = 0; mi < 4; mi++)
    for (int ni = 0; ni < 4; ni++) acc[mi][ni] = (f32x4){0.f, 0.f, 0.f, 0.f};

  for (int k0 = 0; k0 < 512; k0 += 64) {
    __syncthreads();
    for (int i = 0; i < 4; i++) {
      int ch = i * 256 + tid;
      int row = ch >> 3, c = ch & 7;
      int cs = c ^ (row & 7);
      gload_lds16(A + (size_t)(m0 + row) * 512 + k0 + cs * 8, &As[ch * 8]);
      gload_lds16(B + (size_t)(n0 + row) * 512 + k0 + cs * 8, &Bs[ch * 8]);
    }
    __syncthreads();
    for (int h = 0; h < 2; h++) {
      bf16x8 af[4], bfv[4];
      for (int mi = 0; mi < 4; mi++) {
        int rr = wm + mi * 16 + qr;
        int cc = (h * 4 + quad) ^ (rr & 7);
        af[mi] = *(bf16x8*)&As[rr * 64 + cc * 8];
      }
      for (int ni = 0; ni < 4; ni++) {
        int rr = wn + ni * 16 + qr;
        int cc = (h * 4 + quad) ^ (rr & 7);
        bfv[ni] = *(bf16x8*)&Bs[rr * 64 + cc * 8];
      }
      for (int mi = 0; mi < 4; mi++)
        for (int ni = 0; ni < 4; ni++) acc[mi][ni] = MFMA(af[mi], bfv[ni], acc[mi][ni]);
    }
  }

  int slice = blockIdx.y * 2 + (wave & 1);   // 32 slices of 64 keys each
  float* Lp = Lpart + (size_t)slice * 16384 + b * 2048;
  for (int mi = 0; mi < 4; mi++) {
    int rowb = m0 + wm + mi * 16 + quad * 4;
    for (int r = 0; r < 4; r++) {
      float s = 0.f;
      bf16* prow = Pb + (size_t)(rowb + r) * 2048 + n0 + wn + qr;
      for (int ni = 0; ni < 4; ni++) {
        float e = exp2f(acc[mi][ni][r] - M0);
        prow[ni * 16] = (bf16)e;
        s += e;
      }
      s += __shfl_xor(s, 1);
      s += __shfl_xor(s, 2);
      s += __shfl_xor(s, 4);
      s += __shfl_xor(s, 8);
      if (qr == 0) Lp[rowb + r] = s;
    }
  }
}

// ---------------------------------------------------------------------------
// Kernel 4: PV GEMM, 128x128, BK=64. Folds the l-reduction (k_lred deleted):
// first 128 threads build Linv_s for this block's 128 q-rows.
// A = P[b] [2048x2048], B = Vtp[b] [512x2048] (h-major, keys contig).
// ---------------------------------------------------------------------------
__global__ __launch_bounds__(256, 3) void k_pv(const bf16* __restrict__ P,
                                               const bf16* __restrict__ Vtp,
                                               const float* __restrict__ Lpart,
                                               float* __restrict__ out) {
  __shared__ bf16 As[128 * 64];
  __shared__ bf16 Bs[128 * 64];
  __shared__ float Linv_s[128];
  int b = blockIdx.z;
  const bf16* A = P + (size_t)b * 2048 * 2048;
  const bf16* B = Vtp + (size_t)b * 512 * 2048;
  int m0 = blockIdx.x * 128, n0 = blockIdx.y * 128;   // m over q, n over h
  int tid = threadIdx.x;
  int wave = tid >> 6, lane = tid & 63, qr = lane & 15, quad = lane >> 4;
  int wm = (wave >> 1) * 64, wn = (wave & 1) * 64;

  if (tid < 128) {
    float s = 0.f;
    for (int j = 0; j < 32; j++) s += Lpart[(size_t)j * 16384 + b * 2048 + m0 + tid];
    Linv_s[tid] = 1.0f / s;
  }

  f32x4 acc[4][4];
  for (int mi = 0; mi < 4; mi++)
    for (int ni = 0; ni < 4; ni++) acc[mi][ni] = (f32x4){0.f, 0.f, 0.f, 0.f};

  for (int k0 = 0; k0 < 2048; k0 += 64) {
    __syncthreads();
    for (int i = 0; i < 4; i++) {
      int ch = i * 256 + tid;
      int row = ch >> 3, c = ch & 7;
      int cs = c ^ (row & 7);
      gload_lds16(A + (size_t)(m0 + row) * 2048 + k0 + cs * 8, &As[ch * 8]);
      gload_lds16(B + (size_t)(n0 + row) * 2048 + k0 + cs * 8, &Bs[ch * 8]);
    }
    __syncthreads();
    for (int h = 0; h < 2; h++) {
      bf16x8 af[4], bfv[4];
      for (int mi = 0; mi < 4; mi++) {
        int rr = wm + mi * 16 + qr;
        int cc = (h * 4 + quad) ^ (rr & 7);
        af[mi] = *(bf16x8*)&As[rr * 64 + cc * 8];
      }
      for (int ni = 0; ni < 4; ni++) {
        int rr = wn + ni * 16 + qr;
        int cc = (h * 4 + quad) ^ (rr & 7);
        bfv[ni] = *(bf16x8*)&Bs[rr * 64 + cc * 8];
      }
      for (int mi = 0; mi < 4; mi++)
        for (int ni = 0; ni < 4; ni++) acc[mi][ni] = MFMA(af[mi], bfv[ni], acc[mi][ni]);
    }
  }

  for (int mi = 0; mi < 4; mi++) {
    int rowl = wm + mi * 16 + quad * 4;      // local q row base
    float linv[4];
    for (int r = 0; r < 4; r++) linv[r] = Linv_s[rowl + r];
    for (int ni = 0; ni < 4; ni++) {
      int col = n0 + wn + ni * 16 + qr;
      float* og = out + (size_t)(b * 2048 + m0 + rowl) * 512 + col;
      for (int r = 0; r < 4; r++) og[(size_t)r * 512] = acc[mi][ni][r] * linv[r];
    }
  }
}

// ---------------------------------------------------------------------------
extern "C" void kernel_launch(void* const* d_in, const int* in_sizes, int n_in,
                              void* d_out, int out_size, void* d_ws, size_t ws_size,
                              hipStream_t stream) {
  (void)in_sizes; (void)n_in; (void)out_size; (void)ws_size;
  const float* q  = (const float*)d_in[0];
  const float* k  = (const float*)d_in[1];
  const float* v  = (const float*)d_in[2];
  const float* Wq = (const float*)d_in[3];
  const float* bq = (const float*)d_in[4];
  const float* Wk = (const float*)d_in[5];
  const float* bk = (const float*)d_in[6];
  const float* Wv = (const float*)d_in[7];
  const float* bv = (const float*)d_in[8];
  float* out = (float*)d_out;

  char* ws = (char*)d_ws;
  bf16* Wt     = (bf16*)(ws);                 // 1,572,864 B
  bf16* Qp     = (bf16*)(ws + 1572864);       // 16 MiB
  bf16* Kp     = (bf16*)(ws + 18350080);      // 16 MiB
  bf16* Vtp    = (bf16*)(ws + 35127296);      // 16 MiB (written by k_proj z=2)
  bf16* P      = (bf16*)(ws + 51904512);      // 64 MiB
  float* Lpart = (float*)(ws + 119013376);    // 2 MiB  (total ~115.4 MiB)

  k_wtrans<<<dim3(16, 16, 3), dim3(32, 8, 1), 0, stream>>>(Wq, Wk, Wv, Wt);
  k_proj<<<dim3(128, 4, 3), 256, 0, stream>>>(q, k, v, Wt, bq, bk, bv, Qp, Kp, Vtp);
  k_qk<<<dim3(16, 16, 8), 256, 0, stream>>>(Qp, Kp, P, Lpart);
  k_pv<<<dim3(16, 4, 8), 256, 0, stream>>>(P, Vtp, Lpart, out);
}